// Round 6
// baseline (354.031 us; speedup 1.0000x reference)
//
#include <hip/hip_runtime.h>
#include <hip/hip_bf16.h>

typedef __attribute__((ext_vector_type(8))) short short8;
typedef __attribute__((ext_vector_type(4))) short short4v;
typedef __attribute__((ext_vector_type(4))) float f32x4;

#define B_ 2
#define S_ 2048
#define HID_ 2048
#define H_ 16
#define KV_ 8
#define D_ 128
#define SCALE_ 0.08838834764831845f
#define SC2_ 0.12751743f          /* SCALE_ * log2(e) */
#define THRRAW_ 62.7f             /* 8 / SC2_ : defer-max threshold in raw units */

__device__ inline short f2bf(float f) {
    union { __hip_bfloat16 h; short s; } u;
    u.h = __float2bfloat16(f);
    return u.s;
}
__device__ inline float bf2f(short s) {
    union { short s; __hip_bfloat16 h; } u;
    u.s = s;
    return __bfloat162float(u.h);
}
__device__ inline float ex2(float x) {   // 2^x via v_exp_f32 (native base-2)
    float r; asm("v_exp_f32 %0, %1" : "=v"(r) : "v"(x)); return r;
}

// async global->LDS, 16B per lane; LDS dest is wave-uniform base + lane*16
__device__ inline void gld16(const short* g, short* l) {
    __builtin_amdgcn_global_load_lds(
        (const __attribute__((address_space(1))) unsigned int*)g,
        (__attribute__((address_space(3))) unsigned int*)l, 16, 0, 0);
}

// ---------------- merged prep: all fp32->bf16 conversions + cos/sin mix --
__device__ inline int mrope_axis(int d) {
    int m = d & 63;
    return m < 21 ? 0 : (m < 42 ? 1 : 2);
}
__global__ __launch_bounds__(256) void prep(const float* __restrict__ hid,
                                            const float* __restrict__ qw_,
                                            const float* __restrict__ kw_,
                                            const float* __restrict__ vw_,
                                            const float* __restrict__ ow_,
                                            const float* __restrict__ cosp,
                                            const float* __restrict__ sinp,
                                            short* __restrict__ Hb,
                                            short* __restrict__ Wqkv,
                                            short* __restrict__ Owb,
                                            float* __restrict__ cm,
                                            float* __restrict__ sm) {
    int bid = blockIdx.x;
    if (bid < 20480) {
        const float* src; short* dst; int base;
        if (bid < 8192)       { src = hid; dst = Hb;              base = bid; }
        else if (bid < 12288) { src = qw_; dst = Wqkv;            base = bid - 8192; }
        else if (bid < 14336) { src = kw_; dst = Wqkv + 4194304;  base = bid - 12288; }
        else if (bid < 16384) { src = vw_; dst = Wqkv + 6291456;  base = bid - 14336; }
        else                  { src = ow_; dst = Owb;             base = bid - 16384; }
        int i = base * 1024 + threadIdx.x * 4;
        float4 v = *(const float4*)(&src[i]);
        short4v o;
        o.x = f2bf(v.x); o.y = f2bf(v.y); o.z = f2bf(v.z); o.w = f2bf(v.w);
        *(short4v*)(&dst[i]) = o;
    } else {
        const size_t AX = (size_t)B_ * S_ * D_;
        int i0 = (bid - 20480) * 1024 + threadIdx.x * 4;
#pragma unroll
        for (int k = 0; k < 4; ++k) {
            int idx = i0 + k;
            int d = idx & (D_ - 1);
            size_t src = (size_t)mrope_axis(d) * AX + idx;
            cm[idx] = cosp[src];
            sm[idx] = sinp[src];
        }
    }
}

// ---------------- generic bf16 GEMM (B^T), fp32 out (O-projection) -------
// 128x128 tile, BK=64, gld16 staging with XOR-swizzled granules (conflict-free)
__global__ __launch_bounds__(256) void gemm_bt(const short* __restrict__ A,
                                               const short* __restrict__ B,
                                               float* __restrict__ C,
                                               int M, int N, int K) {
    __shared__ __align__(16) short As[128 * 64];
    __shared__ __align__(16) short Bs[128 * 64];
    int tid = threadIdx.x;
    int wave = tid >> 6, lane = tid & 63;
    int m16 = lane & 15, quad = lane >> 4;
    int wr = wave >> 1, wc = wave & 1;
    int m0 = blockIdx.y * 128, n0 = blockIdx.x * 128;
    int srow = lane >> 3;                       // 0..7 row within 8-row issue
    int scol = ((lane & 7) ^ srow) << 3;        // swizzled source granule (shorts)
    f32x4 acc[4][4] = {};
    for (int k0 = 0; k0 < K; k0 += 64) {
#pragma unroll
        for (int i = 0; i < 4; ++i) {
            gld16(&A[(size_t)(m0 + wave * 32 + i * 8 + srow) * K + k0 + scol],
                  &As[(wave * 32 + i * 8) * 64]);
            gld16(&B[(size_t)(n0 + wave * 32 + i * 8 + srow) * K + k0 + scol],
                  &Bs[(wave * 32 + i * 8) * 64]);
        }
        __syncthreads();
        short8 a[4][2], b[4][2];
#pragma unroll
        for (int i = 0; i < 4; ++i)
#pragma unroll
            for (int kk = 0; kk < 2; ++kk) {
                int gsw = (((kk << 2) + quad) ^ (m16 & 7)) << 3;
                a[i][kk] = *(const short8*)(&As[(wr * 64 + i * 16 + m16) * 64 + gsw]);
                b[i][kk] = *(const short8*)(&Bs[(wc * 64 + i * 16 + m16) * 64 + gsw]);
            }
#pragma unroll
        for (int kk = 0; kk < 2; ++kk)
#pragma unroll
            for (int i = 0; i < 4; ++i)
#pragma unroll
                for (int j = 0; j < 4; ++j)
                    acc[i][j] = __builtin_amdgcn_mfma_f32_16x16x32_bf16(a[i][kk], b[j][kk],
                                                                        acc[i][j], 0, 0, 0);
        __syncthreads();
    }
#pragma unroll
    for (int i = 0; i < 4; ++i) {
        int row = m0 + wr * 64 + i * 16 + quad * 4;
#pragma unroll
        for (int j = 0; j < 4; ++j) {
            int col = n0 + wc * 64 + j * 16 + m16;
#pragma unroll
            for (int r = 0; r < 4; ++r)
                C[(size_t)(row + r) * N + col] = acc[i][j][r];
        }
    }
}

// ---------------- QKV GEMM (256x256, 4-phase/K-tile, counted vmcnt) ------
// R5-proven: uniform vmcnt(4) at every phase end (>=2-phase issue->wait
// slack). Epilogue: V blocks fused transpose; Q/K raw bf16 (RMSNorm/RoPE
// in qkv_post -> no epilogue register pressure).

#define VM4 asm volatile("s_waitcnt vmcnt(4)" ::: "memory")
#define VM2 asm volatile("s_waitcnt vmcnt(2)" ::: "memory")
#define VM0 asm volatile("s_waitcnt vmcnt(0)" ::: "memory")

#define LDA(dst, QI)                                                               \
    _Pragma("unroll") for (int ii = 0; ii < 4; ++ii)                               \
        _Pragma("unroll") for (int kk = 0; kk < 2; ++kk)                           \
            dst[ii][kk] = *(const short8*)&lds[RA +                                \
                (wr * 128 + ((QI) * 4 + ii) * 16 + m16) * 64 +                     \
                ((((kk << 2) + quad) ^ (m16 & 7)) << 3)]

#define LDB(dst, QJ)                                                               \
    _Pragma("unroll") for (int jj = 0; jj < 2; ++jj)                               \
        _Pragma("unroll") for (int kk = 0; kk < 2; ++kk)                           \
            dst[jj][kk] = *(const short8*)&lds[RB +                                \
                ((QJ) * 128 + wc * 32 + jj * 16 + m16) * 64 +                      \
                ((((kk << 2) + quad) ^ (m16 & 7)) << 3)]

#define MM(ua, ub, QI, QJ)                                                         \
    _Pragma("unroll") for (int kk = 0; kk < 2; ++kk)                               \
        _Pragma("unroll") for (int ii = 0; ii < 4; ++ii)                           \
            _Pragma("unroll") for (int jj = 0; jj < 2; ++jj)                       \
                acc[(QI) * 4 + ii][(QJ) * 2 + jj] =                                \
                    __builtin_amdgcn_mfma_f32_16x16x32_bf16(                       \
                        ua[ii][kk], ub[jj][kk],                                    \
                        acc[(QI) * 4 + ii][(QJ) * 2 + jj], 0, 0, 0)

#define STGA(q) do {                                                               \
    int r_ = (wave << 3) + (lane >> 3);                                            \
    int g_ = (lane & 7) ^ (r_ & 7);                                                \
    gld16(&Am[(size_t)(m0 + (q) * 64 + r_) * 2048 + kc + (g_ << 3)],               \
          &lds[PA + (q) * 4096 + (wave << 9)]);                                    \
} while (0)
#define STGB(h, c) do {                                                            \
    int s_ = (wave << 3) + (lane >> 3);                                            \
    int sl_ = (h) * 128 + (c) * 64 + s_;                                           \
    int rr_ = ((sl_ >> 5) & 3) * 64 + (h) * 32 + (sl_ & 31);                       \
    int g_ = (lane & 7) ^ (sl_ & 7);                                               \
    gld16(&Bm[(size_t)(n0 + rr_) * 2048 + kc + (g_ << 3)],                         \
          &lds[PB + ((h) * 128 + (c) * 64) * 64 + (wave << 9)]);                   \
} while (0)

#define PH(LOADS, STG, MFMAS, WAITOP) do {                                         \
    LOADS;                                                                         \
    STG;                                                                           \
    __builtin_amdgcn_sched_barrier(0);                                             \
    __builtin_amdgcn_s_barrier();                                                  \
    asm volatile("s_waitcnt lgkmcnt(0)" ::: "memory");                             \
    __builtin_amdgcn_sched_barrier(0);                                             \
    __builtin_amdgcn_s_setprio(1);                                                 \
    MFMAS;                                                                         \
    __builtin_amdgcn_s_setprio(0);                                                 \
    WAITOP;                                                                        \
    __builtin_amdgcn_sched_barrier(0);                                             \
    __builtin_amdgcn_s_barrier();                                                  \
} while (0)

__global__ __launch_bounds__(512) void gemm_qkv(const short* __restrict__ Am,
                                                const short* __restrict__ Bm,
                                                short* __restrict__ Cq,
                                                short* __restrict__ Vb) {
    __shared__ __align__(16) char smem[131072];
    short* lds = (short*)smem;
    int tid = threadIdx.x;
    int wave = tid >> 6, lane = tid & 63;
    int m16 = lane & 15, quad = lane >> 4;
    int wr = wave >> 2, wc = wave & 3;
    // XCD-aware bijective swizzle (nwg=256, 256%8==0): XCD c gets 2 A-panels
    int orig = blockIdx.y * 16 + blockIdx.x;
    int swz = (orig & 7) * 32 + (orig >> 3);
    int bx = swz & 15, by = swz >> 4;
    int m0 = by * 256, n0 = bx * 256;
    int x = bx;
    f32x4 acc[8][4] = {};

    // ---- prologue: stage tile 0 into buf0, full drain ----
    {
        const int kc = 0, PA = 0, PB = 16384;
        STGA(0); STGA(1); STGA(2); STGA(3);
        STGB(0, 0); STGB(0, 1); STGB(1, 0); STGB(1, 1);
        VM0;
        __builtin_amdgcn_sched_barrier(0);
        __builtin_amdgcn_s_barrier();
    }

    short8 af[4][2], bfX[2][2], bfY[2][2];
    for (int t = 0; t < 31; ++t) {
        const int RA = (t & 1) << 15, RB = RA + 16384;
        const int PA = RA ^ 32768, PB = PA + 16384;
        const int kc = (t + 1) << 6;
        PH({ LDA(af, 0); LDB(bfX, 0); }, { STGA(0); STGA(2); },       MM(af, bfX, 0, 0), VM4);
        PH({ LDB(bfY, 1); },             { STGB(0, 0); STGB(0, 1); }, MM(af, bfY, 0, 1), VM4);
        PH({ LDA(af, 1); },              { STGB(1, 0); STGB(1, 1); }, MM(af, bfY, 1, 1), VM4);
        PH({ ; },                        { STGA(1); STGA(3); },       MM(af, bfX, 1, 0), VM4);
    }
    {   // tail tile 31 (buf1): drain ramp VM2 -> VM0 (2-phase slack each)
        const int RA = 32768, RB = RA + 16384;
        PH({ LDA(af, 0); LDB(bfX, 0); }, { ; }, MM(af, bfX, 0, 0), VM2);
        PH({ LDB(bfY, 1); },             { ; }, MM(af, bfY, 0, 1), VM0);
        PH({ LDA(af, 1); },              { ; }, MM(af, bfY, 1, 1), );
        PH({ ; },                        { ; }, MM(af, bfX, 1, 0), );
    }

    // ---- epilogue ----
    int bb = m0 >> 11, s0 = m0 & (S_ - 1);
    if (x >= 12) {
        // V: transpose to [B,KV,D,S]; block covers kv heads kv0, kv0+1
        short* T = (short*)smem;   // [256 cols][136 rows-pad]
        int kv0 = (x - 12) << 1;
        for (int hs = 0; hs < 2; ++hs) {
            __syncthreads();
            if (wr == hs) {
#pragma unroll
                for (int i = 0; i < 8; ++i)
#pragma unroll
                    for (int j = 0; j < 4; ++j) {
                        short4v v4;
#pragma unroll
                        for (int r = 0; r < 4; ++r) v4[r] = f2bf(acc[i][j][r]);
                        *(short4v*)&T[(wc * 64 + j * 16 + m16) * 136 + i * 16 + quad * 4] = v4;
                    }
            }
            __syncthreads();
#pragma unroll
            for (int it = 0; it < 8; ++it) {
                int e = (it * 512 + tid) * 8;
                int col = e >> 7, ro = e & 127;
                int kvh = col >> 7, d = col & 127;
                *(short8*)&Vb[(((size_t)(bb * KV_ + kv0 + kvh)) * D_ + d) * S_ +
                              s0 + hs * 128 + ro] =
                    *(const short8*)&T[col * 136 + ro];
            }
        }
    } else {
        // Q/K: raw bf16 C write (RMSNorm+RoPE done by qkv_post)
#pragma unroll
        for (int i = 0; i < 8; ++i) {
            int row = m0 + wr * 128 + i * 16 + quad * 4;
#pragma unroll
            for (int j = 0; j < 4; ++j) {
                int col = n0 + wc * 64 + j * 16 + m16;
#pragma unroll
                for (int r = 0; r < 4; ++r)
                    Cq[(size_t)(row + r) * 3072 + col] = f2bf(acc[i][j][r]);
            }
        }
    }
}

#undef PH
#undef LDA
#undef LDB
#undef MM
#undef STGA
#undef STGB
#undef VM4
#undef VM2
#undef VM0

// ---------------- qkv_post: RMSNorm + mRoPE for Q/K from raw C -----------
#define TP 136
__global__ __launch_bounds__(256) void qkv_post(const short* __restrict__ Cq,
                                                const float* __restrict__ qnw,
                                                const float* __restrict__ knw,
                                                const float* __restrict__ cm,
                                                const float* __restrict__ sm,
                                                short* __restrict__ Qb,
                                                short* __restrict__ Kb) {
    __shared__ __align__(16) short T[128 * TP];   // 34816 B
    __shared__ float sq[128];
    __shared__ float rsA[128];
    int tid = threadIdx.x;
    int hk = blockIdx.x;                 // 0..15 Q head, 16..23 K head
    int m0 = blockIdx.y * 128;
    int b = m0 >> 11, s0 = m0 & (S_ - 1);
#pragma unroll
    for (int it = 0; it < 8; ++it) {
        int idx = it * 256 + tid;
        int row = idx >> 4, g = idx & 15;
        short8 v = *(const short8*)&Cq[(size_t)(m0 + row) * 3072 + hk * 128 + g * 8];
        *(short8*)&T[row * TP + g * 8] = v;
        float s = 0.f;
#pragma unroll
        for (int k = 0; k < 8; ++k) { float f = bf2f(v[k]); s += f * f; }
#pragma unroll
        for (int msk = 8; msk >= 1; msk >>= 1) s += __shfl_xor(s, msk, 64);
        if ((tid & 15) == 0) sq[row] = s;
    }
    __syncthreads();
    if (tid < 128) rsA[tid] = rsqrtf(sq[tid] * (1.0f / 128.0f) + 1e-6f);
    __syncthreads();
    const float* nw = (hk < 16) ? qnw : knw;
    short* outp = (hk < 16) ? (Qb + ((size_t)(b * H_ + hk)) * S_ * D_)
                            : (Kb + ((size_t)(b * KV_ + hk - 16)) * S_ * D_);
    size_t cmb = ((size_t)(b * S_ + s0)) * D_;
#pragma unroll
    for (int it = 0; it < 8; ++it) {
        int e = (it * 256 + tid) * 8;
        int row = e >> 7, colc = e & 127;
        int pc = colc ^ 64;
        float rs = rsA[row];
        float sg = (colc < 64) ? -1.f : 1.f;
        short8 nv = *(const short8*)&T[row * TP + colc];
        short8 pv = *(const short8*)&T[row * TP + pc];
        float4 cA = *(const float4*)&cm[cmb + (size_t)row * D_ + colc];
        float4 cB = *(const float4*)&cm[cmb + (size_t)row * D_ + colc + 4];
        float4 sA = *(const float4*)&sm[cmb + (size_t)row * D_ + colc];
        float4 sB = *(const float4*)&sm[cmb + (size_t)row * D_ + colc + 4];
        float4 wA = *(const float4*)&nw[colc];
        float4 wB = *(const float4*)&nw[colc + 4];
        float4 wpA = *(const float4*)&nw[pc];
        float4 wpB = *(const float4*)&nw[pc + 4];
        float cs[8] = {cA.x, cA.y, cA.z, cA.w, cB.x, cB.y, cB.z, cB.w};
        float sn[8] = {sA.x, sA.y, sA.z, sA.w, sB.x, sB.y, sB.z, sB.w};
        float wv[8] = {wA.x, wA.y, wA.z, wA.w, wB.x, wB.y, wB.z, wB.w};
        float wp[8] = {wpA.x, wpA.y, wpA.z, wpA.w, wpB.x, wpB.y, wpB.z, wpB.w};
        short8 o;
#pragma unroll
        for (int k = 0; k < 8; ++k) {
            float xv = bf2f(nv[k]) * rs * wv[k];
            float pvv = bf2f(pv[k]) * rs * wp[k];
            o[k] = f2bf(xv * cs[k] + sg * pvv * sn[k]);
        }
        *(short8*)&outp[(size_t)(s0 + row) * D_ + colc] = o;
    }
}

// ---------------- flash attention (causal, GQA), transposed-S form -------
// R6: 128-row q-tiles, 2 row-sets per wave (set0 rows qt*128+w*16+m16,
// set1 = +64). K-frags loaded ONCE per chunk, reused for both sets' QK^T.
// Staging bytes + barriers per unit compute halved (272 vs 528 chunks,
// exact same causal area: set0 skipped on final chunk). Softmax: defer-max
// (skip O-rescale when max growth <= 8 exp-units) + base-2 domain with
// fused scale (1 v_fma + 1 v_exp per score). Ps reused serially across
// sets (LDS stays 74752 B -> 2 blocks/CU).
#define VPAD 72
__global__ __launch_bounds__(256) void attn_fa(const short* __restrict__ Qb,
                                               const short* __restrict__ Kb,
                                               const short* __restrict__ Vb,
                                               short* __restrict__ Ab) {
    __shared__ __align__(16) short Ks[2][64 * 128];   // 32768 B
    __shared__ __align__(16) short Vs[2][128 * 64];   // 32768 B
    __shared__ __align__(16) short Ps[4][16 * VPAD];  //  9216 B
    int tid = threadIdx.x;
    int wave = tid >> 6, lane = tid & 63;
    int m16 = lane & 15, quad = lane >> 4;
    int bh = blockIdx.x;
    int h = bh & 15, b = bh >> 4;
    int qt = 15 - blockIdx.y;          // heavy causal tiles dispatch first
    int kv = h >> 1;
    const short* Qp = Qb + (size_t)(b * H_ + h) * S_ * D_;
    const short* Kp = Kb + (size_t)(b * KV_ + kv) * S_ * D_;
    const short* Vp = Vb + (size_t)(b * KV_ + kv) * D_ * S_;
    int qrow0 = qt * 128 + wave * 16 + m16;   // set0: lower half of tile
    int qrow1 = qrow0 + 64;                   // set1: upper half
    short8 qf0[4], qf1[4];
#pragma unroll
    for (int c = 0; c < 4; ++c) {
        qf0[c] = *(const short8*)(&Qp[(size_t)qrow0 * D_ + c * 32 + quad * 8]);
        qf1[c] = *(const short8*)(&Qp[(size_t)qrow1 * D_ + c * 32 + quad * 8]);
    }
    f32x4 o0[8] = {}, o1[8] = {};      // O^T: row d = j*16+quad*4+r, col q = m16
    float m0r = -1e30f, l0r = 0.f, m1r = -1e30f, l1r = 0.f;
    int nchunks = 2 * qt + 2;

    // prologue: stage chunk 0 into buf 0 (wave w stages calls w*4..w*4+3)
#pragma unroll
    for (int j = 0; j < 4; ++j) {
        int idx = wave * 4 + j;
        int r = idx * 4 + (lane >> 4);               // K row 0..63
        int g = (lane & 15) ^ (r & 7);               // pre-swizzled src granule
        gld16(&Kp[(size_t)r * D_ + g * 8], &Ks[0][idx * 512]);
    }
#pragma unroll
    for (int j = 0; j < 4; ++j) {
        int idx = wave * 4 + j;
        int r = idx * 8 + (lane >> 3);               // V row (d) 0..127
        int g = (lane & 7) ^ (r & 7);
        gld16(&Vp[(size_t)r * S_ + g * 8], &Vs[0][idx * 512]);
    }
    __syncthreads();                                 // drains vmcnt(0) + barrier

// softmax with defer-max, base-2 domain, raw-unit scores
#define SMAX(sv, mr, lr, oA, p) do {                                              \
    float mx = -1e30f;                                                            \
    _Pragma("unroll") for (int nt = 0; nt < 4; ++nt)                              \
        _Pragma("unroll") for (int r = 0; r < 4; ++r) mx = fmaxf(mx, sv[nt][r]);  \
    mx = fmaxf(mx, __shfl_xor(mx, 16, 64));                                       \
    mx = fmaxf(mx, __shfl_xor(mx, 32, 64));                                       \
    if (!__all(mx - mr <= THRRAW_)) {                                             \
        float mn = fmaxf(mr, mx);                                                 \
        float al = ex2((mr - mn) * SC2_);                                         \
        _Pragma("unroll") for (int j = 0; j < 8; ++j) {                           \
            f32x4 t = oA[j];                                                      \
            _Pragma("unroll") for (int r = 0; r < 4; ++r) t[r] *= al;             \
            oA[j] = t;                                                            \
        }                                                                         \
        lr *= al; mr = mn;                                                        \
    }                                                                             \
    float ms = mr * SC2_;                                                         \
    float sum = 0.f;                                                              \
    _Pragma("unroll") for (int nt = 0; nt < 4; ++nt)                              \
        _Pragma("unroll") for (int r = 0; r < 4; ++r) {                           \
            p[nt][r] = ex2(__builtin_fmaf(sv[nt][r], SC2_, -ms));                 \
            sum += p[nt][r];                                                      \
        }                                                                         \
    sum += __shfl_xor(sum, 16, 64);                                               \
    sum += __shfl_xor(sum, 32, 64);                                               \
    lr += sum;                                                                    \
} while (0)

// P store (wave-private Ps, reused across sets; in-wave lgkm ordering) + PV
#define PVSTEP(p, oA) do {                                                        \
    _Pragma("unroll") for (int nt = 0; nt < 4; ++nt) {                            \
        short4v pk;                                                               \
        _Pragma("unroll") for (int r = 0; r < 4; ++r) pk[r] = f2bf(p[nt][r]);     \
        *(short4v*)&Ps[wave][m16 * VPAD + nt * 16 + quad * 4] = pk;               \
    }                                                                             \
    __builtin_amdgcn_s_setprio(1);                                                \
    _Pragma("unroll") for (int kk = 0; kk < 2; ++kk) {                            \
        short8 pf = *(const short8*)(&Ps[wave][m16 * VPAD + kk * 32 + quad * 8]); \
        _Pragma("unroll") for (int j = 0; j < 8; ++j) {                           \
            short8 vfr = *(const short8*)(&Vs[cur][(j * 16 + m16) * 64 +          \
                                 ((((kk << 2) + quad) ^ (m16 & 7)) << 3)]);       \
            oA[j] = __builtin_amdgcn_mfma_f32_16x16x32_bf16(vfr, pf, oA[j], 0, 0, 0); \
        }                                                                         \
    }                                                                             \
    __builtin_amdgcn_s_setprio(0);                                                \
} while (0)

    for (int kc = 0; kc < nchunks; ++kc) {
        int k0 = kc * 64;
        int cur = kc & 1;
        // stage next chunk into the other buffer (overlaps this chunk's compute)
        if (kc + 1 < nchunks) {
            int nk0 = k0 + 64, nb = cur ^ 1;
#pragma unroll
            for (int j = 0; j < 4; ++j) {
                int idx = wave * 4 + j;
                int r = idx * 4 + (lane >> 4);
                int g = (lane & 15) ^ (r & 7);
                gld16(&Kp[(size_t)(nk0 + r) * D_ + g * 8], &Ks[nb][idx * 512]);
            }
#pragma unroll
            for (int j = 0; j < 4; ++j) {
                int idx = wave * 4 + j;
                int r = idx * 8 + (lane >> 3);
                int g = (lane & 7) ^ (r & 7);
                gld16(&Vp[(size_t)r * S_ + nk0 + g * 8], &Vs[nb][idx * 512]);
            }
        }
        bool do0 = (kc < nchunks - 1);       // set0 fully masked on last chunk
        bool dg0 = (kc == nchunks - 2);      // set0 diagonal chunk
        bool dg1 = (kc == nchunks - 1);      // set1 diagonal chunk
        // S^T both sets: K-frag loaded once, 2 MFMA per frag
        float sv0[4][4], sv1[4][4];
        __builtin_amdgcn_s_setprio(1);
#pragma unroll
        for (int nt = 0; nt < 4; ++nt) {
            short8 kfr[4];
#pragma unroll
            for (int c = 0; c < 4; ++c)
                kfr[c] = *(const short8*)(&Ks[cur][(nt * 16 + m16) * 128 +
                                      ((((c << 2) + quad) ^ (m16 & 7)) << 3)]);
            f32x4 f1a = {};
#pragma unroll
            for (int c = 0; c < 4; ++c)
                f1a = __builtin_amdgcn_mfma_f32_16x16x32_bf16(kfr[c], qf1[c], f1a, 0, 0, 0);
            if (do0) {
                f32x4 f0a = {};
#pragma unroll
                for (int c = 0; c < 4; ++c)
                    f0a = __builtin_amdgcn_mfma_f32_16x16x32_bf16(kfr[c], qf0[c], f0a, 0, 0, 0);
#pragma unroll
                for (int r = 0; r < 4; ++r) sv0[nt][r] = f0a[r];
            }
#pragma unroll
            for (int r = 0; r < 4; ++r) sv1[nt][r] = f1a[r];
        }
        __builtin_amdgcn_s_setprio(0);
        if (dg0) {
#pragma unroll
            for (int nt = 0; nt < 4; ++nt)
#pragma unroll
                for (int r = 0; r < 4; ++r) {
                    int key = k0 + nt * 16 + quad * 4 + r;
                    if (key > qrow0) sv0[nt][r] = -1e30f;
                }
        }
        if (dg1) {
#pragma unroll
            for (int nt = 0; nt < 4; ++nt)
#pragma unroll
                for (int r = 0; r < 4; ++r) {
                    int key = k0 + nt * 16 + quad * 4 + r;
                    if (key > qrow1) sv1[nt][r] = -1e30f;
                }
        }
        if (do0) {
            float p0[4][4];
            SMAX(sv0, m0r, l0r, o0, p0);
            PVSTEP(p0, o0);
        }
        {
            float p1[4][4];
            SMAX(sv1, m1r, l1r, o1, p1);
            PVSTEP(p1, o1);
        }
        __syncthreads();   // implicit vmcnt(0)+lgkmcnt(0) drain: next-buf stages
                           // landed AND all waves done reading cur before reuse
    }
#undef SMAX
#undef PVSTEP
    // epilogue: lane holds O^T[d = j*16+quad*4+r][q = m16] for both sets
    float il0 = 1.0f / l0r, il1 = 1.0f / l1r;
    size_t base0 = ((size_t)(b * S_ + qrow0)) * (H_ * D_) + h * D_;
    size_t base1 = ((size_t)(b * S_ + qrow1)) * (H_ * D_) + h * D_;
#pragma unroll
    for (int j = 0; j < 8; ++j) {
        short4v ov0, ov1;
#pragma unroll
        for (int r = 0; r < 4; ++r) {
            ov0[r] = f2bf(o0[j][r] * il0);
            ov1[r] = f2bf(o1[j][r] * il1);
        }
        *(short4v*)&Ab[base0 + j * 16 + quad * 4] = ov0;
        *(short4v*)&Ab[base1 + j * 16 + quad * 4] = ov1;
    }
}

// -------------------------------------------------------------------------
extern "C" void kernel_launch(void* const* d_in, const int* in_sizes, int n_in,
                              void* d_out, int out_size, void* d_ws, size_t ws_size,
                              hipStream_t stream) {
    const float* hid  = (const float*)d_in[0];
    const float* cosp = (const float*)d_in[1];
    const float* sinp = (const float*)d_in[2];
    const float* q_w  = (const float*)d_in[3];
    const float* k_w  = (const float*)d_in[4];
    const float* v_w  = (const float*)d_in[5];
    const float* o_w  = (const float*)d_in[6];
    const float* qnw  = (const float*)d_in[7];
    const float* knw  = (const float*)d_in[8];

    char* w = (char*)d_ws;
    short* Hb    = (short*)w;  w += (size_t)4096 * 2048 * 2;              // 16MB
    short* Wqkv  = (short*)w;  w += (size_t)4096 * 2048 * 2;              // 16MB
    short* Owb   = (short*)w;  w += (size_t)2048 * 2048 * 2;              // 8MB
    short* Qb    = (short*)w;  w += (size_t)B_ * H_ * S_ * D_ * 2;        // 16MB
    short* Kb    = (short*)w;  w += (size_t)B_ * KV_ * S_ * D_ * 2;       // 8MB
    short* Vb    = (short*)w;  w += (size_t)B_ * KV_ * D_ * S_ * 2;       // 8MB
    short* Ab    = (short*)w;  w += (size_t)4096 * 2048 * 2;              // 16MB
    float* cos_m = (float*)w;  w += (size_t)B_ * S_ * D_ * 4;             // 2MB
    float* sin_m = (float*)w;  w += (size_t)B_ * S_ * D_ * 4;             // 2MB
    short* Cq    = (short*)w;  w += (size_t)4096 * 3072 * 2;              // 24MB

    // 1. single prep kernel: all bf16 conversions + mrope cos/sin premix
    prep<<<20992, 256, 0, stream>>>(hid, q_w, k_w, v_w, o_w, cosp, sinp,
                                    Hb, Wqkv, Owb, cos_m, sin_m);

    // 2. QKV GEMM (256^2, counted-vmcnt): Q/K raw -> Cq, V fused-transpose -> Vb
    gemm_qkv<<<dim3(16, 16), 512, 0, stream>>>(Hb, Wqkv, Cq, Vb);

    // 2b. RMSNorm + mRoPE epilogue pass for Q/K
    qkv_post<<<dim3(24, 32), 256, 0, stream>>>(Cq, qnw, knw, cos_m, sin_m, Qb, Kb);

    // 3. flash attention (128-row q-tiles, 2 sets/wave) -> Ab [B,S,H*D] bf16
    attn_fa<<<dim3(32, 16), 256, 0, stream>>>(Qb, Kb, Vb, Ab);

    // 4. O projection: [4096 x 2048] x [2048 x 2048]^T -> d_out fp32
    gemm_bt<<<dim3(16, 32), 256, 0, stream>>>(Ab, Owb, (float*)d_out, 4096, 2048, 2048);
}

// Round 7
// 323.806 us; speedup vs baseline: 1.0933x; 1.0933x over previous
//
#include <hip/hip_runtime.h>
#include <hip/hip_bf16.h>

typedef __attribute__((ext_vector_type(8))) short short8;
typedef __attribute__((ext_vector_type(4))) short short4v;
typedef __attribute__((ext_vector_type(4))) float f32x4;

#define B_ 2
#define S_ 2048
#define HID_ 2048
#define H_ 16
#define KV_ 8
#define D_ 128
#define SCALE_ 0.08838834764831845f
#define SC2_ 0.12751743f          /* SCALE_ * log2(e) */
#define THRRAW_ 62.7f             /* 8 / SC2_ : defer-max threshold in raw units */

__device__ inline short f2bf(float f) {
    union { __hip_bfloat16 h; short s; } u;
    u.h = __float2bfloat16(f);
    return u.s;
}
__device__ inline float bf2f(short s) {
    union { short s; __hip_bfloat16 h; } u;
    u.s = s;
    return __bfloat162float(u.h);
}
__device__ inline float ex2(float x) {   // 2^x via v_exp_f32 (native base-2)
    float r; asm("v_exp_f32 %0, %1" : "=v"(r) : "v"(x)); return r;
}

// async global->LDS, 16B per lane; LDS dest is wave-uniform base + lane*16
__device__ inline void gld16(const short* g, short* l) {
    __builtin_amdgcn_global_load_lds(
        (const __attribute__((address_space(1))) unsigned int*)g,
        (__attribute__((address_space(3))) unsigned int*)l, 16, 0, 0);
}

// ---------------- merged prep: all fp32->bf16 conversions + cos/sin mix --
__device__ inline int mrope_axis(int d) {
    int m = d & 63;
    return m < 21 ? 0 : (m < 42 ? 1 : 2);
}
__global__ __launch_bounds__(256) void prep(const float* __restrict__ hid,
                                            const float* __restrict__ qw_,
                                            const float* __restrict__ kw_,
                                            const float* __restrict__ vw_,
                                            const float* __restrict__ ow_,
                                            const float* __restrict__ cosp,
                                            const float* __restrict__ sinp,
                                            short* __restrict__ Hb,
                                            short* __restrict__ Wqkv,
                                            short* __restrict__ Owb,
                                            float* __restrict__ cm,
                                            float* __restrict__ sm) {
    int bid = blockIdx.x;
    if (bid < 20480) {
        const float* src; short* dst; int base;
        if (bid < 8192)       { src = hid; dst = Hb;              base = bid; }
        else if (bid < 12288) { src = qw_; dst = Wqkv;            base = bid - 8192; }
        else if (bid < 14336) { src = kw_; dst = Wqkv + 4194304;  base = bid - 12288; }
        else if (bid < 16384) { src = vw_; dst = Wqkv + 6291456;  base = bid - 14336; }
        else                  { src = ow_; dst = Owb;             base = bid - 16384; }
        int i = base * 1024 + threadIdx.x * 4;
        float4 v = *(const float4*)(&src[i]);
        short4v o;
        o.x = f2bf(v.x); o.y = f2bf(v.y); o.z = f2bf(v.z); o.w = f2bf(v.w);
        *(short4v*)(&dst[i]) = o;
    } else {
        const size_t AX = (size_t)B_ * S_ * D_;
        int i0 = (bid - 20480) * 1024 + threadIdx.x * 4;
#pragma unroll
        for (int k = 0; k < 4; ++k) {
            int idx = i0 + k;
            int d = idx & (D_ - 1);
            size_t src = (size_t)mrope_axis(d) * AX + idx;
            cm[idx] = cosp[src];
            sm[idx] = sinp[src];
        }
    }
}

// ---------------- generic bf16 GEMM (B^T), fp32 out (O-projection) -------
// 128x128 tile, BK=64, gld16 staging with XOR-swizzled granules (conflict-free)
__global__ __launch_bounds__(256) void gemm_bt(const short* __restrict__ A,
                                               const short* __restrict__ B,
                                               float* __restrict__ C,
                                               int M, int N, int K) {
    __shared__ __align__(16) short As[128 * 64];
    __shared__ __align__(16) short Bs[128 * 64];
    int tid = threadIdx.x;
    int wave = tid >> 6, lane = tid & 63;
    int m16 = lane & 15, quad = lane >> 4;
    int wr = wave >> 1, wc = wave & 1;
    int m0 = blockIdx.y * 128, n0 = blockIdx.x * 128;
    int srow = lane >> 3;                       // 0..7 row within 8-row issue
    int scol = ((lane & 7) ^ srow) << 3;        // swizzled source granule (shorts)
    f32x4 acc[4][4] = {};
    for (int k0 = 0; k0 < K; k0 += 64) {
#pragma unroll
        for (int i = 0; i < 4; ++i) {
            gld16(&A[(size_t)(m0 + wave * 32 + i * 8 + srow) * K + k0 + scol],
                  &As[(wave * 32 + i * 8) * 64]);
            gld16(&B[(size_t)(n0 + wave * 32 + i * 8 + srow) * K + k0 + scol],
                  &Bs[(wave * 32 + i * 8) * 64]);
        }
        __syncthreads();
        short8 a[4][2], b[4][2];
#pragma unroll
        for (int i = 0; i < 4; ++i)
#pragma unroll
            for (int kk = 0; kk < 2; ++kk) {
                int gsw = (((kk << 2) + quad) ^ (m16 & 7)) << 3;
                a[i][kk] = *(const short8*)(&As[(wr * 64 + i * 16 + m16) * 64 + gsw]);
                b[i][kk] = *(const short8*)(&Bs[(wc * 64 + i * 16 + m16) * 64 + gsw]);
            }
#pragma unroll
        for (int kk = 0; kk < 2; ++kk)
#pragma unroll
            for (int i = 0; i < 4; ++i)
#pragma unroll
                for (int j = 0; j < 4; ++j)
                    acc[i][j] = __builtin_amdgcn_mfma_f32_16x16x32_bf16(a[i][kk], b[j][kk],
                                                                        acc[i][j], 0, 0, 0);
        __syncthreads();
    }
#pragma unroll
    for (int i = 0; i < 4; ++i) {
        int row = m0 + wr * 64 + i * 16 + quad * 4;
#pragma unroll
        for (int j = 0; j < 4; ++j) {
            int col = n0 + wc * 64 + j * 16 + m16;
#pragma unroll
            for (int r = 0; r < 4; ++r)
                C[(size_t)(row + r) * N + col] = acc[i][j][r];
        }
    }
}

// ---------------- QKV GEMM (256x256, 4-phase/K-tile, counted vmcnt) ------
// R5-proven: uniform vmcnt(4) at every phase end (>=2-phase issue->wait
// slack). Epilogue: V blocks fused transpose; Q/K raw bf16 (RMSNorm/RoPE
// in qkv_post -> no epilogue register pressure).

#define VM4 asm volatile("s_waitcnt vmcnt(4)" ::: "memory")
#define VM2 asm volatile("s_waitcnt vmcnt(2)" ::: "memory")
#define VM0 asm volatile("s_waitcnt vmcnt(0)" ::: "memory")

#define LDA(dst, QI)                                                               \
    _Pragma("unroll") for (int ii = 0; ii < 4; ++ii)                               \
        _Pragma("unroll") for (int kk = 0; kk < 2; ++kk)                           \
            dst[ii][kk] = *(const short8*)&lds[RA +                                \
                (wr * 128 + ((QI) * 4 + ii) * 16 + m16) * 64 +                     \
                ((((kk << 2) + quad) ^ (m16 & 7)) << 3)]

#define LDB(dst, QJ)                                                               \
    _Pragma("unroll") for (int jj = 0; jj < 2; ++jj)                               \
        _Pragma("unroll") for (int kk = 0; kk < 2; ++kk)                           \
            dst[jj][kk] = *(const short8*)&lds[RB +                                \
                ((QJ) * 128 + wc * 32 + jj * 16 + m16) * 64 +                      \
                ((((kk << 2) + quad) ^ (m16 & 7)) << 3)]

#define MM(ua, ub, QI, QJ)                                                         \
    _Pragma("unroll") for (int kk = 0; kk < 2; ++kk)                               \
        _Pragma("unroll") for (int ii = 0; ii < 4; ++ii)                           \
            _Pragma("unroll") for (int jj = 0; jj < 2; ++jj)                       \
                acc[(QI) * 4 + ii][(QJ) * 2 + jj] =                                \
                    __builtin_amdgcn_mfma_f32_16x16x32_bf16(                       \
                        ua[ii][kk], ub[jj][kk],                                    \
                        acc[(QI) * 4 + ii][(QJ) * 2 + jj], 0, 0, 0)

#define STGA(q) do {                                                               \
    int r_ = (wave << 3) + (lane >> 3);                                            \
    int g_ = (lane & 7) ^ (r_ & 7);                                                \
    gld16(&Am[(size_t)(m0 + (q) * 64 + r_) * 2048 + kc + (g_ << 3)],               \
          &lds[PA + (q) * 4096 + (wave << 9)]);                                    \
} while (0)
#define STGB(h, c) do {                                                            \
    int s_ = (wave << 3) + (lane >> 3);                                            \
    int sl_ = (h) * 128 + (c) * 64 + s_;                                           \
    int rr_ = ((sl_ >> 5) & 3) * 64 + (h) * 32 + (sl_ & 31);                       \
    int g_ = (lane & 7) ^ (sl_ & 7);                                               \
    gld16(&Bm[(size_t)(n0 + rr_) * 2048 + kc + (g_ << 3)],                         \
          &lds[PB + ((h) * 128 + (c) * 64) * 64 + (wave << 9)]);                   \
} while (0)

#define PH(LOADS, STG, MFMAS, WAITOP) do {                                         \
    LOADS;                                                                         \
    STG;                                                                           \
    __builtin_amdgcn_sched_barrier(0);                                             \
    __builtin_amdgcn_s_barrier();                                                  \
    asm volatile("s_waitcnt lgkmcnt(0)" ::: "memory");                             \
    __builtin_amdgcn_sched_barrier(0);                                             \
    __builtin_amdgcn_s_setprio(1);                                                 \
    MFMAS;                                                                         \
    __builtin_amdgcn_s_setprio(0);                                                 \
    WAITOP;                                                                        \
    __builtin_amdgcn_sched_barrier(0);                                             \
    __builtin_amdgcn_s_barrier();                                                  \
} while (0)

__global__ __launch_bounds__(512) void gemm_qkv(const short* __restrict__ Am,
                                                const short* __restrict__ Bm,
                                                short* __restrict__ Cq,
                                                short* __restrict__ Vb) {
    __shared__ __align__(16) char smem[131072];
    short* lds = (short*)smem;
    int tid = threadIdx.x;
    int wave = tid >> 6, lane = tid & 63;
    int m16 = lane & 15, quad = lane >> 4;
    int wr = wave >> 2, wc = wave & 3;
    // XCD-aware bijective swizzle (nwg=256, 256%8==0): XCD c gets 2 A-panels
    int orig = blockIdx.y * 16 + blockIdx.x;
    int swz = (orig & 7) * 32 + (orig >> 3);
    int bx = swz & 15, by = swz >> 4;
    int m0 = by * 256, n0 = bx * 256;
    int x = bx;
    f32x4 acc[8][4] = {};

    // ---- prologue: stage tile 0 into buf0, full drain ----
    {
        const int kc = 0, PA = 0, PB = 16384;
        STGA(0); STGA(1); STGA(2); STGA(3);
        STGB(0, 0); STGB(0, 1); STGB(1, 0); STGB(1, 1);
        VM0;
        __builtin_amdgcn_sched_barrier(0);
        __builtin_amdgcn_s_barrier();
    }

    short8 af[4][2], bfX[2][2], bfY[2][2];
    for (int t = 0; t < 31; ++t) {
        const int RA = (t & 1) << 15, RB = RA + 16384;
        const int PA = RA ^ 32768, PB = PA + 16384;
        const int kc = (t + 1) << 6;
        PH({ LDA(af, 0); LDB(bfX, 0); }, { STGA(0); STGA(2); },       MM(af, bfX, 0, 0), VM4);
        PH({ LDB(bfY, 1); },             { STGB(0, 0); STGB(0, 1); }, MM(af, bfY, 0, 1), VM4);
        PH({ LDA(af, 1); },              { STGB(1, 0); STGB(1, 1); }, MM(af, bfY, 1, 1), VM4);
        PH({ ; },                        { STGA(1); STGA(3); },       MM(af, bfX, 1, 0), VM4);
    }
    {   // tail tile 31 (buf1): drain ramp VM2 -> VM0 (2-phase slack each)
        const int RA = 32768, RB = RA + 16384;
        PH({ LDA(af, 0); LDB(bfX, 0); }, { ; }, MM(af, bfX, 0, 0), VM2);
        PH({ LDB(bfY, 1); },             { ; }, MM(af, bfY, 0, 1), VM0);
        PH({ LDA(af, 1); },              { ; }, MM(af, bfY, 1, 1), );
        PH({ ; },                        { ; }, MM(af, bfX, 1, 0), );
    }

    // ---- epilogue ----
    int bb = m0 >> 11, s0 = m0 & (S_ - 1);
    if (x >= 12) {
        // V: transpose to [B,KV,D,S]; block covers kv heads kv0, kv0+1
        short* T = (short*)smem;   // [256 cols][136 rows-pad]
        int kv0 = (x - 12) << 1;
        for (int hs = 0; hs < 2; ++hs) {
            __syncthreads();
            if (wr == hs) {
#pragma unroll
                for (int i = 0; i < 8; ++i)
#pragma unroll
                    for (int j = 0; j < 4; ++j) {
                        short4v v4;
#pragma unroll
                        for (int r = 0; r < 4; ++r) v4[r] = f2bf(acc[i][j][r]);
                        *(short4v*)&T[(wc * 64 + j * 16 + m16) * 136 + i * 16 + quad * 4] = v4;
                    }
            }
            __syncthreads();
#pragma unroll
            for (int it = 0; it < 8; ++it) {
                int e = (it * 512 + tid) * 8;
                int col = e >> 7, ro = e & 127;
                int kvh = col >> 7, d = col & 127;
                *(short8*)&Vb[(((size_t)(bb * KV_ + kv0 + kvh)) * D_ + d) * S_ +
                              s0 + hs * 128 + ro] =
                    *(const short8*)&T[col * 136 + ro];
            }
        }
    } else {
        // Q/K: raw bf16 C write (RMSNorm+RoPE done by qkv_post)
#pragma unroll
        for (int i = 0; i < 8; ++i) {
            int row = m0 + wr * 128 + i * 16 + quad * 4;
#pragma unroll
            for (int j = 0; j < 4; ++j) {
                int col = n0 + wc * 64 + j * 16 + m16;
#pragma unroll
                for (int r = 0; r < 4; ++r)
                    Cq[(size_t)(row + r) * 3072 + col] = f2bf(acc[i][j][r]);
            }
        }
    }
}

#undef PH
#undef LDA
#undef LDB
#undef MM
#undef STGA
#undef STGB
#undef VM4
#undef VM2
#undef VM0

// ---------------- qkv_post: RMSNorm + mRoPE for Q/K from raw C -----------
#define TP 136
__global__ __launch_bounds__(256) void qkv_post(const short* __restrict__ Cq,
                                                const float* __restrict__ qnw,
                                                const float* __restrict__ knw,
                                                const float* __restrict__ cm,
                                                const float* __restrict__ sm,
                                                short* __restrict__ Qb,
                                                short* __restrict__ Kb) {
    __shared__ __align__(16) short T[128 * TP];   // 34816 B
    __shared__ float sq[128];
    __shared__ float rsA[128];
    int tid = threadIdx.x;
    int hk = blockIdx.x;                 // 0..15 Q head, 16..23 K head
    int m0 = blockIdx.y * 128;
    int b = m0 >> 11, s0 = m0 & (S_ - 1);
#pragma unroll
    for (int it = 0; it < 8; ++it) {
        int idx = it * 256 + tid;
        int row = idx >> 4, g = idx & 15;
        short8 v = *(const short8*)&Cq[(size_t)(m0 + row) * 3072 + hk * 128 + g * 8];
        *(short8*)&T[row * TP + g * 8] = v;
        float s = 0.f;
#pragma unroll
        for (int k = 0; k < 8; ++k) { float f = bf2f(v[k]); s += f * f; }
#pragma unroll
        for (int msk = 8; msk >= 1; msk >>= 1) s += __shfl_xor(s, msk, 64);
        if ((tid & 15) == 0) sq[row] = s;
    }
    __syncthreads();
    if (tid < 128) rsA[tid] = rsqrtf(sq[tid] * (1.0f / 128.0f) + 1e-6f);
    __syncthreads();
    const float* nw = (hk < 16) ? qnw : knw;
    short* outp = (hk < 16) ? (Qb + ((size_t)(b * H_ + hk)) * S_ * D_)
                            : (Kb + ((size_t)(b * KV_ + hk - 16)) * S_ * D_);
    size_t cmb = ((size_t)(b * S_ + s0)) * D_;
#pragma unroll
    for (int it = 0; it < 8; ++it) {
        int e = (it * 256 + tid) * 8;
        int row = e >> 7, colc = e & 127;
        int pc = colc ^ 64;
        float rs = rsA[row];
        float sg = (colc < 64) ? -1.f : 1.f;
        short8 nv = *(const short8*)&T[row * TP + colc];
        short8 pv = *(const short8*)&T[row * TP + pc];
        float4 cA = *(const float4*)&cm[cmb + (size_t)row * D_ + colc];
        float4 cB = *(const float4*)&cm[cmb + (size_t)row * D_ + colc + 4];
        float4 sA = *(const float4*)&sm[cmb + (size_t)row * D_ + colc];
        float4 sB = *(const float4*)&sm[cmb + (size_t)row * D_ + colc + 4];
        float4 wA = *(const float4*)&nw[colc];
        float4 wB = *(const float4*)&nw[colc + 4];
        float4 wpA = *(const float4*)&nw[pc];
        float4 wpB = *(const float4*)&nw[pc + 4];
        float cs[8] = {cA.x, cA.y, cA.z, cA.w, cB.x, cB.y, cB.z, cB.w};
        float sn[8] = {sA.x, sA.y, sA.z, sA.w, sB.x, sB.y, sB.z, sB.w};
        float wv[8] = {wA.x, wA.y, wA.z, wA.w, wB.x, wB.y, wB.z, wB.w};
        float wp[8] = {wpA.x, wpA.y, wpA.z, wpA.w, wpB.x, wpB.y, wpB.z, wpB.w};
        short8 o;
#pragma unroll
        for (int k = 0; k < 8; ++k) {
            float xv = bf2f(nv[k]) * rs * wv[k];
            float pvv = bf2f(pv[k]) * rs * wp[k];
            o[k] = f2bf(xv * cs[k] + sg * pvv * sn[k]);
        }
        *(short8*)&outp[(size_t)(s0 + row) * D_ + colc] = o;
    }
}

// ---------------- flash attention (causal, GQA), transposed-S form -------
// R7: R5 structure exactly (64-row q-tiles, 1024 blocks, 1 set/wave —
// proven 76 µs; R6's 128-row 2-set variant doubled the per-block critical
// path with only 512 blocks -> tail-bound, reverted). Only change vs R5:
// softmax in base-2 domain with fused scale (1 v_fma + 1 v_exp per score)
// + T13 defer-max (skip O-rescale when max growth <= 8 exp-units).
#define VPAD 72
__global__ __launch_bounds__(256) void attn_fa(const short* __restrict__ Qb,
                                               const short* __restrict__ Kb,
                                               const short* __restrict__ Vb,
                                               short* __restrict__ Ab) {
    __shared__ __align__(16) short Ks[2][64 * 128];   // 32768 B
    __shared__ __align__(16) short Vs[2][128 * 64];   // 32768 B
    __shared__ __align__(16) short Ps[4][16 * VPAD];  //  9216 B
    int tid = threadIdx.x;
    int wave = tid >> 6, lane = tid & 63;
    int m16 = lane & 15, quad = lane >> 4;
    int bh = blockIdx.x;
    int h = bh & 15, b = bh >> 4;
    int qt = 31 - blockIdx.y;          // heavy causal tiles dispatch first
    int kv = h >> 1;
    const short* Qp = Qb + (size_t)(b * H_ + h) * S_ * D_;
    const short* Kp = Kb + (size_t)(b * KV_ + kv) * S_ * D_;
    const short* Vp = Vb + (size_t)(b * KV_ + kv) * D_ * S_;
    int q_base = qt * 64 + wave * 16;
    int qrow = q_base + m16;           // this lane's q row
    short8 qf[4];
#pragma unroll
    for (int c = 0; c < 4; ++c)
        qf[c] = *(const short8*)(&Qp[(size_t)(q_base + m16) * D_ + c * 32 + quad * 8]);
    f32x4 o_acc[8] = {};               // O^T: row d = j*16+quad*4+r, col q = m16
    float m_r = -1e30f, l_r = 0.f;     // per-lane state for q = m16 (raw units)
    int nchunks = qt + 1;

    // prologue: stage chunk 0 into buf 0 (wave w stages calls w*4..w*4+3)
#pragma unroll
    for (int j = 0; j < 4; ++j) {
        int idx = wave * 4 + j;
        int r = idx * 4 + (lane >> 4);               // K row 0..63
        int g = (lane & 15) ^ (r & 7);               // pre-swizzled src granule
        gld16(&Kp[(size_t)r * D_ + g * 8], &Ks[0][idx * 512]);
    }
#pragma unroll
    for (int j = 0; j < 4; ++j) {
        int idx = wave * 4 + j;
        int r = idx * 8 + (lane >> 3);               // V row (d) 0..127
        int g = (lane & 7) ^ (r & 7);
        gld16(&Vp[(size_t)r * S_ + g * 8], &Vs[0][idx * 512]);
    }
    __syncthreads();                                 // drains vmcnt(0) + barrier

    for (int kc = 0; kc < nchunks; ++kc) {
        int k0 = kc * 64;
        int cur = kc & 1;
        // stage next chunk into the other buffer (overlaps this chunk's compute)
        if (kc + 1 < nchunks) {
            int nk0 = k0 + 64, nb = cur ^ 1;
#pragma unroll
            for (int j = 0; j < 4; ++j) {
                int idx = wave * 4 + j;
                int r = idx * 4 + (lane >> 4);
                int g = (lane & 15) ^ (r & 7);
                gld16(&Kp[(size_t)(nk0 + r) * D_ + g * 8], &Ks[nb][idx * 512]);
            }
#pragma unroll
            for (int j = 0; j < 4; ++j) {
                int idx = wave * 4 + j;
                int r = idx * 8 + (lane >> 3);
                int g = (lane & 7) ^ (r & 7);
                gld16(&Vp[(size_t)r * S_ + nk0 + g * 8], &Vs[nb][idx * 512]);
            }
        }
        // S^T: 4 key tiles of 16; mfma(a=K, b=Q) => row=key, col=q (raw units)
        float sv[4][4];
        __builtin_amdgcn_s_setprio(1);
#pragma unroll
        for (int nt = 0; nt < 4; ++nt) {
            f32x4 facc = {};
#pragma unroll
            for (int c = 0; c < 4; ++c) {
                short8 kfr = *(const short8*)(&Ks[cur][(nt * 16 + m16) * 128 +
                                                      ((((c << 2) + quad) ^ (m16 & 7)) << 3)]);
                facc = __builtin_amdgcn_mfma_f32_16x16x32_bf16(kfr, qf[c], facc, 0, 0, 0);
            }
            if (kc == qt) {
#pragma unroll
                for (int r = 0; r < 4; ++r) {
                    int key = k0 + nt * 16 + quad * 4 + r;
                    sv[nt][r] = (key <= qrow) ? facc[r] : -1e30f;
                }
            } else {
#pragma unroll
                for (int r = 0; r < 4; ++r) sv[nt][r] = facc[r];
            }
        }
        __builtin_amdgcn_s_setprio(0);
        // online softmax (base-2 domain, defer-max): scores stay in raw units;
        // p = 2^(s*SC2 - m*SC2), rescale only when max grows > 8 exp-units
        float mx = -1e30f;
#pragma unroll
        for (int nt = 0; nt < 4; ++nt)
#pragma unroll
            for (int r = 0; r < 4; ++r) mx = fmaxf(mx, sv[nt][r]);
        mx = fmaxf(mx, __shfl_xor(mx, 16, 64));
        mx = fmaxf(mx, __shfl_xor(mx, 32, 64));
        if (!__all(mx - m_r <= THRRAW_)) {
            float mn = fmaxf(m_r, mx);
            float al = ex2((m_r - mn) * SC2_);
#pragma unroll
            for (int j = 0; j < 8; ++j) {
                f32x4 t = o_acc[j];
#pragma unroll
                for (int r = 0; r < 4; ++r) t[r] *= al;
                o_acc[j] = t;
            }
            l_r *= al;
            m_r = mn;
        }
        float ms = m_r * SC2_;
        float p[4][4], sum = 0.f;
#pragma unroll
        for (int nt = 0; nt < 4; ++nt)
#pragma unroll
            for (int r = 0; r < 4; ++r) {
                p[nt][r] = ex2(__builtin_fmaf(sv[nt][r], SC2_, -ms));
                sum += p[nt][r];
            }
        sum += __shfl_xor(sum, 16, 64);
        sum += __shfl_xor(sum, 32, 64);
        l_r += sum;
        // P store: lane holds P[q=m16][key nt*16+quad*4 .. +3] -> one b64 per nt
#pragma unroll
        for (int nt = 0; nt < 4; ++nt) {
            short4v pk;
#pragma unroll
            for (int r = 0; r < 4; ++r) pk[r] = f2bf(p[nt][r]);
            *(short4v*)&Ps[wave][m16 * VPAD + nt * 16 + quad * 4] = pk;
        }
        // O^T += mfma(a=V^T-frag, b=P-frag): two K=32 sub-chunks
        __builtin_amdgcn_s_setprio(1);
#pragma unroll
        for (int kk = 0; kk < 2; ++kk) {
            short8 pf = *(const short8*)(&Ps[wave][m16 * VPAD + kk * 32 + quad * 8]);
#pragma unroll
            for (int j = 0; j < 8; ++j) {
                short8 vfr = *(const short8*)(&Vs[cur][(j * 16 + m16) * 64 +
                                                       ((((kk << 2) + quad) ^ (m16 & 7)) << 3)]);
                o_acc[j] = __builtin_amdgcn_mfma_f32_16x16x32_bf16(vfr, pf, o_acc[j], 0, 0, 0);
            }
        }
        __builtin_amdgcn_s_setprio(0);
        __syncthreads();   // implicit vmcnt(0)+lgkmcnt(0) drain: next-buf stages
                           // landed AND all waves done reading cur before reuse
    }
    // epilogue: lane holds O^T[d = j*16+quad*4+r][q = m16]
    float inv_l = 1.0f / l_r;
    size_t base = ((size_t)(b * S_ + qrow)) * (H_ * D_) + h * D_;
#pragma unroll
    for (int j = 0; j < 8; ++j) {
        short4v ov;
#pragma unroll
        for (int r = 0; r < 4; ++r) ov[r] = f2bf(o_acc[j][r] * inv_l);
        *(short4v*)&Ab[base + j * 16 + quad * 4] = ov;
    }
}

// -------------------------------------------------------------------------
extern "C" void kernel_launch(void* const* d_in, const int* in_sizes, int n_in,
                              void* d_out, int out_size, void* d_ws, size_t ws_size,
                              hipStream_t stream) {
    const float* hid  = (const float*)d_in[0];
    const float* cosp = (const float*)d_in[1];
    const float* sinp = (const float*)d_in[2];
    const float* q_w  = (const float*)d_in[3];
    const float* k_w  = (const float*)d_in[4];
    const float* v_w  = (const float*)d_in[5];
    const float* o_w  = (const float*)d_in[6];
    const float* qnw  = (const float*)d_in[7];
    const float* knw  = (const float*)d_in[8];

    char* w = (char*)d_ws;
    short* Hb    = (short*)w;  w += (size_t)4096 * 2048 * 2;              // 16MB
    short* Wqkv  = (short*)w;  w += (size_t)4096 * 2048 * 2;              // 16MB
    short* Owb   = (short*)w;  w += (size_t)2048 * 2048 * 2;              // 8MB
    short* Qb    = (short*)w;  w += (size_t)B_ * H_ * S_ * D_ * 2;        // 16MB
    short* Kb    = (short*)w;  w += (size_t)B_ * KV_ * S_ * D_ * 2;       // 8MB
    short* Vb    = (short*)w;  w += (size_t)B_ * KV_ * D_ * S_ * 2;       // 8MB
    short* Ab    = (short*)w;  w += (size_t)4096 * 2048 * 2;              // 16MB
    float* cos_m = (float*)w;  w += (size_t)B_ * S_ * D_ * 4;             // 2MB
    float* sin_m = (float*)w;  w += (size_t)B_ * S_ * D_ * 4;             // 2MB
    short* Cq    = (short*)w;  w += (size_t)4096 * 3072 * 2;              // 24MB

    // 1. single prep kernel: all bf16 conversions + mrope cos/sin premix
    prep<<<20992, 256, 0, stream>>>(hid, q_w, k_w, v_w, o_w, cosp, sinp,
                                    Hb, Wqkv, Owb, cos_m, sin_m);

    // 2. QKV GEMM (256^2, counted-vmcnt): Q/K raw -> Cq, V fused-transpose -> Vb
    gemm_qkv<<<dim3(16, 16), 512, 0, stream>>>(Hb, Wqkv, Cq, Vb);

    // 2b. RMSNorm + mRoPE epilogue pass for Q/K
    qkv_post<<<dim3(24, 32), 256, 0, stream>>>(Cq, qnw, knw, cos_m, sin_m, Qb, Kb);

    // 3. flash attention (transposed-S form) -> Ab [B,S,H*D] bf16
    attn_fa<<<dim3(32, 32), 256, 0, stream>>>(Qb, Kb, Vb, Ab);

    // 4. O projection: [4096 x 2048] x [2048 x 2048]^T -> d_out fp32
    gemm_bt<<<dim3(16, 32), 256, 0, stream>>>(Ab, Owb, (float*)d_out, 4096, 2048, 2048);
}